// Round 1
// baseline (172.377 us; speedup 1.0000x reference)
//
#include <hip/hip_runtime.h>
#include <math.h>

#define B_SZ 4
#define C_IN 64
#define H_ 24
#define W_ 24
#define HW_ 576

// ---------------- Kernel 1: BatchNorm (batch stats) + affine, writes xn ----
__global__ __launch_bounds__(256)
void bn_norm_kernel(const float* __restrict__ x, const float* __restrict__ gamma,
                    const float* __restrict__ beta, float* __restrict__ xn) {
  const int c = blockIdx.x;          // one block per channel
  const int tid = threadIdx.x;
  __shared__ float red[8];
  float s = 0.f, ss = 0.f;
  for (int j = tid; j < B_SZ * HW_; j += 256) {
    int b = j / HW_, i = j - b * HW_;
    float v = x[(b * C_IN + c) * HW_ + i];
    s += v; ss = fmaf(v, v, ss);
  }
#pragma unroll
  for (int off = 32; off > 0; off >>= 1) {
    s += __shfl_down(s, off);
    ss += __shfl_down(ss, off);
  }
  if ((tid & 63) == 0) { red[tid >> 6] = s; red[4 + (tid >> 6)] = ss; }
  __syncthreads();
  s  = red[0] + red[1] + red[2] + red[3];
  ss = red[4] + red[5] + red[6] + red[7];
  const float inv_n = 1.f / (B_SZ * HW_);
  float mean = s * inv_n;
  float var  = ss * inv_n - mean * mean;
  float a  = rsqrtf(var + 1e-5f) * gamma[c];
  float bi = fmaf(-mean, a, beta[c]);
  for (int j = tid; j < B_SZ * HW_; j += 256) {
    int b = j / HW_, i = j - b * HW_;
    int idx = (b * C_IN + c) * HW_ + i;
    xn[idx] = fmaf(x[idx], a, bi);
  }
}

// ---------------- Kernel 2/4: 3x3 conv, pad 1, stride 1, Cin=64 ------------
// grid.x = B * (OC/OCG); 256 threads. Each thread owns pixel-pairs
// pp = tid (+256): y = pp/12, x0 = (pp%12)*2. ic staged 8 planes at a time
// into zero-padded LDS (26 rows x 28 cols as float2). Weights are read with
// wave-uniform indices (scalarize to s_load).
template <int OCG>
__global__ __launch_bounds__(256)
void conv3x3_kernel(const float* __restrict__ in, const float* __restrict__ wgt,
                    const float* __restrict__ resid, float* __restrict__ out,
                    int OC) {
  const int ogc = OC / OCG;
  const int b   = blockIdx.x / ogc;
  const int oc0 = (blockIdx.x % ogc) * OCG;
  const int tid = threadIdx.x;
  __shared__ float2 plane2[8][26 * 14];

  float acc[OCG][2][2];
#pragma unroll
  for (int o = 0; o < OCG; ++o)
#pragma unroll
    for (int sl = 0; sl < 2; ++sl) { acc[o][sl][0] = 0.f; acc[o][sl][1] = 0.f; }

  int ybase[2], xbase[2];
  bool valid[2];
  {
    int pp0 = tid;        ybase[0] = pp0 / 12; xbase[0] = (pp0 % 12) * 2; valid[0] = true;
    int pp1 = tid + 256;  ybase[1] = pp1 / 12; xbase[1] = (pp1 % 12) * 2; valid[1] = (pp1 < 288);
  }
  const int lbase[2] = { ybase[0] * 14 + (xbase[0] >> 1),
                         ybase[1] * 14 + (xbase[1] >> 1) };

  for (int ic0 = 0; ic0 < C_IN; ic0 += 8) {
    __syncthreads();
    for (int e = tid; e < 8 * 26 * 14; e += 256) {
      int p  = e / (26 * 14);
      int r  = e - p * (26 * 14);
      int py = r / 14, px2 = r - py * 14;
      int yy = py - 1;
      int xa = px2 * 2 - 1;
      float fx = 0.f, fy = 0.f;
      if ((unsigned)yy < (unsigned)H_) {
        const float* src = in + ((b * C_IN + ic0 + p) * HW_) + yy * W_;
        if ((unsigned)xa < (unsigned)W_)       fx = src[xa];
        if ((unsigned)(xa + 1) < (unsigned)W_) fy = src[xa + 1];
      }
      plane2[p][r] = make_float2(fx, fy);
    }
    __syncthreads();
#pragma unroll
    for (int p = 0; p < 8; ++p) {
      const int ic = ic0 + p;
      float w[OCG][9];
#pragma unroll
      for (int o = 0; o < OCG; ++o)
#pragma unroll
        for (int t = 0; t < 9; ++t)
          w[o][t] = wgt[((oc0 + o) * C_IN + ic) * 9 + t];
#pragma unroll
      for (int sl = 0; sl < 2; ++sl) {
        if (valid[sl]) {
          const int base = lbase[sl];
#pragma unroll
          for (int r3 = 0; r3 < 3; ++r3) {
            float2 f0 = plane2[p][base + r3 * 14];
            float2 f1 = plane2[p][base + r3 * 14 + 1];
#pragma unroll
            for (int o = 0; o < OCG; ++o) {
              acc[o][sl][0] = fmaf(f1.x, w[o][r3 * 3 + 2],
                              fmaf(f0.y, w[o][r3 * 3 + 1],
                              fmaf(f0.x, w[o][r3 * 3 + 0], acc[o][sl][0])));
              acc[o][sl][1] = fmaf(f1.y, w[o][r3 * 3 + 2],
                              fmaf(f1.x, w[o][r3 * 3 + 1],
                              fmaf(f0.y, w[o][r3 * 3 + 0], acc[o][sl][1])));
            }
          }
        }
      }
    }
  }
#pragma unroll
  for (int o = 0; o < OCG; ++o) {
#pragma unroll
    for (int sl = 0; sl < 2; ++sl) {
      if (valid[sl]) {
        int idx = ((b * OC + oc0 + o) * HW_) + ybase[sl] * W_ + xbase[sl];
        float2 r = make_float2(acc[o][sl][0], acc[o][sl][1]);
        if (resid) { r.x += resid[idx]; r.y += resid[idx + 1]; }
        *reinterpret_cast<float2*>(out + idx) = r;
      }
    }
  }
}

// ---------------- Kernel 3: rank-1 attention per (b,c) ---------------------
// out_v[p] = sum_i v[i]*2^(s*k[i]-m) / sum_i 2^(s*k[i]-m),  s = q[p]*scale*log2e
__global__ __launch_bounds__(512)
void attn_kernel(const float* __restrict__ qkv, float* __restrict__ out_v) {
  const int bc = blockIdx.x;
  const int b = bc >> 6, c = bc & 63;
  const float* qp = qkv + (size_t)(b * 192 + c) * HW_;
  const float* kp = qkv + (size_t)(b * 192 + 64 + c) * HW_;
  const float* vp = qkv + (size_t)(b * 192 + 128 + c) * HW_;
  __shared__ float2 kv[HW_];
  __shared__ float red[16];
  const int tid = threadIdx.x;
  float kmax = -1e30f, kmin = 1e30f;
  for (int i = tid; i < HW_; i += 512) {
    float kk = kp[i], vv = vp[i];
    kv[i] = make_float2(kk, vv);
    kmax = fmaxf(kmax, kk); kmin = fminf(kmin, kk);
  }
#pragma unroll
  for (int off = 32; off > 0; off >>= 1) {
    kmax = fmaxf(kmax, __shfl_down(kmax, off));
    kmin = fminf(kmin, __shfl_down(kmin, off));
  }
  const int wid = tid >> 6;
  if ((tid & 63) == 0) { red[wid] = kmax; red[8 + wid] = kmin; }
  __syncthreads();
  kmax = red[0]; kmin = red[8];
#pragma unroll
  for (int w = 1; w < 8; ++w) {
    kmax = fmaxf(kmax, red[w]); kmin = fminf(kmin, red[8 + w]);
  }
  const float scale_l2e = 0.125f * 1.44269504088896341f;  // 1/sqrt(64) * log2(e)
  for (int pix = tid; pix < HW_; pix += 512) {
    float s = qp[pix] * scale_l2e;
    float m = (s >= 0.f) ? s * kmax : s * kmin;
    float num = 0.f, den = 0.f;
    for (int i = 0; i < HW_; ++i) {
      float2 f = kv[i];
      float e = exp2f(fmaf(s, f.x, -m));
      den += e;
      num = fmaf(e, f.y, num);
    }
    out_v[(size_t)(b * C_IN + c) * HW_ + pix] = num / den;
  }
}

// ---------------- launch ---------------------------------------------------
extern "C" void kernel_launch(void* const* d_in, const int* in_sizes, int n_in,
                              void* d_out, int out_size, void* d_ws, size_t ws_size,
                              hipStream_t stream) {
  const float* x     = (const float*)d_in[0];
  const float* gamma = (const float*)d_in[1];
  const float* beta  = (const float*)d_in[2];
  const float* w_qkv = (const float*)d_in[3];
  const float* w_out = (const float*)d_in[4];
  float* out = (float*)d_out;

  float* xn    = (float*)d_ws;                       // 147456 floats
  float* qkv   = xn  + (size_t)B_SZ * C_IN * HW_;    // 442368 floats
  float* out_v = qkv + (size_t)B_SZ * 3 * C_IN * HW_;// 147456 floats

  bn_norm_kernel<<<64, 256, 0, stream>>>(x, gamma, beta, xn);
  conv3x3_kernel<3><<<256, 256, 0, stream>>>(xn, w_qkv, nullptr, qkv, 192);
  attn_kernel<<<256, 512, 0, stream>>>(qkv, out_v);
  conv3x3_kernel<1><<<256, 256, 0, stream>>>(out_v, w_out, x, out, 64);
}

// Round 2
// 137.350 us; speedup vs baseline: 1.2550x; 1.2550x over previous
//
#include <hip/hip_runtime.h>
#include <math.h>

#define B_SZ 4
#define C_IN 64
#define H_ 24
#define W_ 24
#define HW_ 576

// ---------------- Kernel 1: BN batch-stats -> per-channel affine (a,b) -----
__global__ __launch_bounds__(256)
void bn_stats_kernel(const float* __restrict__ x, const float* __restrict__ gamma,
                     const float* __restrict__ beta, float* __restrict__ A,
                     float* __restrict__ Bc) {
  const int c = blockIdx.x;
  const int tid = threadIdx.x;
  __shared__ float red[8];
  float s = 0.f, ss = 0.f;
  for (int j = tid; j < B_SZ * HW_; j += 256) {
    int b = j / HW_, i = j - b * HW_;
    float v = x[(b * C_IN + c) * HW_ + i];
    s += v; ss = fmaf(v, v, ss);
  }
#pragma unroll
  for (int off = 32; off > 0; off >>= 1) {
    s += __shfl_down(s, off);
    ss += __shfl_down(ss, off);
  }
  if ((tid & 63) == 0) { red[tid >> 6] = s; red[4 + (tid >> 6)] = ss; }
  __syncthreads();
  if (tid == 0) {
    s  = red[0] + red[1] + red[2] + red[3];
    ss = red[4] + red[5] + red[6] + red[7];
    const float inv_n = 1.f / (B_SZ * HW_);
    float mean = s * inv_n;
    float var  = ss * inv_n - mean * mean;
    float a = rsqrtf(var + 1e-5f) * gamma[c];
    A[c]  = a;
    Bc[c] = fmaf(-mean, a, beta[c]);
  }
}

// ---------------- Kernel 2/4: 3x3 conv, pad 1, Cin=64, row-band split ------
// grid = B * (OC/OCG) * 2 halves; 160 threads. Threads 0..143 each own one
// horizontal pixel pair of a 12-row band. 8 ic planes staged per iteration
// into zero-padded LDS (14 rows x 14 float2). Optional fused BN affine on
// staging (AFFINE) and fused residual-add on store (RESID).
template <int OCG, bool AFFINE, bool RESID>
__global__ __launch_bounds__(160)
void conv3x3_v2(const float* __restrict__ in, const float* __restrict__ wgt,
                const float* __restrict__ A, const float* __restrict__ Bc,
                const float* __restrict__ resid, float* __restrict__ out,
                int OC) {
  const int G = OC / OCG;
  const int bid = blockIdx.x;
  const int h = bid & 1;
  const int g = (bid >> 1) % G;
  const int b = (bid >> 1) / G;
  const int oc0 = g * OCG;
  const int tid = threadIdx.x;
  const int y0 = h * 12;

  __shared__ float2 sm[8][14 * 14];

  float acc[OCG][2];
#pragma unroll
  for (int o = 0; o < OCG; ++o) { acc[o][0] = 0.f; acc[o][1] = 0.f; }

  const bool active = tid < 144;
  const int yl = tid / 12;    // 0..11 local output row
  const int xj = tid % 12;    // pair column (x = 2*xj)
  const int lb = yl * 14 + xj;

  for (int ic0 = 0; ic0 < C_IN; ic0 += 8) {
    __syncthreads();
    for (int e = tid; e < 8 * 196; e += 160) {
      int p = e / 196, r = e - p * 196;
      int py = r / 14, pxx = r - py * 14;
      int yy = y0 + py - 1;
      int xa = pxx * 2 - 1;
      float fx = 0.f, fy = 0.f;
      if ((unsigned)yy < (unsigned)H_) {
        const float* src = in + ((b * C_IN + ic0 + p) * HW_) + yy * W_;
        float aa = 1.f, bb = 0.f;
        if (AFFINE) { aa = A[ic0 + p]; bb = Bc[ic0 + p]; }
        if ((unsigned)xa < (unsigned)W_)       fx = fmaf(src[xa], aa, bb);
        if ((unsigned)(xa + 1) < (unsigned)W_) fy = fmaf(src[xa + 1], aa, bb);
      }
      sm[p][r] = make_float2(fx, fy);
    }
    __syncthreads();
    if (active) {
#pragma unroll 2
      for (int p = 0; p < 8; ++p) {
        const int ic = ic0 + p;
        float w[OCG][9];
#pragma unroll
        for (int o = 0; o < OCG; ++o)
#pragma unroll
          for (int t = 0; t < 9; ++t)
            w[o][t] = wgt[((oc0 + o) * C_IN + ic) * 9 + t];
        float2 f0a = sm[p][lb],      f1a = sm[p][lb + 1];
        float2 f0b = sm[p][lb + 14], f1b = sm[p][lb + 15];
        float2 f0c = sm[p][lb + 28], f1c = sm[p][lb + 29];
#pragma unroll
        for (int o = 0; o < OCG; ++o) {
          acc[o][0] = fmaf(f0a.x, w[o][0], fmaf(f0a.y, w[o][1], fmaf(f1a.x, w[o][2],
                      fmaf(f0b.x, w[o][3], fmaf(f0b.y, w[o][4], fmaf(f1b.x, w[o][5],
                      fmaf(f0c.x, w[o][6], fmaf(f0c.y, w[o][7], fmaf(f1c.x, w[o][8],
                      acc[o][0])))))))));
          acc[o][1] = fmaf(f0a.y, w[o][0], fmaf(f1a.x, w[o][1], fmaf(f1a.y, w[o][2],
                      fmaf(f0b.y, w[o][3], fmaf(f1b.x, w[o][4], fmaf(f1b.y, w[o][5],
                      fmaf(f0c.y, w[o][6], fmaf(f1c.x, w[o][7], fmaf(f1c.y, w[o][8],
                      acc[o][1])))))))));
        }
      }
    }
  }
  if (active) {
    const int y = y0 + yl, xx = xj * 2;
#pragma unroll
    for (int o = 0; o < OCG; ++o) {
      int idx = ((b * OC + oc0 + o) * HW_) + y * W_ + xx;
      float2 r = make_float2(acc[o][0], acc[o][1]);
      if (RESID) {
        float2 rr = *reinterpret_cast<const float2*>(resid + idx);
        r.x += rr.x; r.y += rr.y;
      }
      *reinterpret_cast<float2*>(out + idx) = r;
    }
  }
}

// ---------------- Kernel 3: rank-1 attention per (b,c), readlane bcast -----
__global__ __launch_bounds__(576)
void attn_v2(const float* __restrict__ qkv, float* __restrict__ out_v) {
  const int bc = blockIdx.x;
  const int b = bc >> 6, c = bc & 63;
  const float* qp = qkv + (size_t)(b * 192 + c) * HW_;
  const float* kp = qkv + (size_t)(b * 192 + 64 + c) * HW_;
  const float* vp = qkv + (size_t)(b * 192 + 128 + c) * HW_;
  __shared__ float2 kvs[HW_];
  __shared__ float red[20];
  const int tid = threadIdx.x;
  const int lane = tid & 63;

  float kk = kp[tid], vv = vp[tid];
  kvs[tid] = make_float2(kk, vv);
  float kmax = kk, kmin = kk;
#pragma unroll
  for (int off = 32; off > 0; off >>= 1) {
    kmax = fmaxf(kmax, __shfl_down(kmax, off));
    kmin = fminf(kmin, __shfl_down(kmin, off));
  }
  const int wid = tid >> 6;
  if (lane == 0) { red[wid] = kmax; red[10 + wid] = kmin; }
  __syncthreads();
  kmax = red[0]; kmin = red[10];
#pragma unroll
  for (int w = 1; w < 9; ++w) {
    kmax = fmaxf(kmax, red[w]); kmin = fminf(kmin, red[10 + w]);
  }

  const float scale_l2e = 0.125f * 1.44269504088896341f;  // 1/sqrt(64)*log2(e)
  const float s = qp[tid] * scale_l2e;
  const float m = (s >= 0.f) ? s * kmax : s * kmin;
  float num0 = 0.f, num1 = 0.f, den0 = 0.f, den1 = 0.f;
  for (int i0 = 0; i0 < HW_; i0 += 64) {
    float2 my = kvs[i0 + lane];
    int ki = __float_as_int(my.x);
    int vi = __float_as_int(my.y);
#pragma unroll
    for (int j = 0; j < 64; j += 2) {
      float k0 = __int_as_float(__builtin_amdgcn_readlane(ki, j));
      float v0 = __int_as_float(__builtin_amdgcn_readlane(vi, j));
      float e0 = exp2f(fmaf(s, k0, -m));
      den0 += e0;
      num0 = fmaf(e0, v0, num0);
      float k1 = __int_as_float(__builtin_amdgcn_readlane(ki, j + 1));
      float v1 = __int_as_float(__builtin_amdgcn_readlane(vi, j + 1));
      float e1 = exp2f(fmaf(s, k1, -m));
      den1 += e1;
      num1 = fmaf(e1, v1, num1);
    }
  }
  out_v[(size_t)(b * C_IN + c) * HW_ + tid] = (num0 + num1) / (den0 + den1);
}

// ---------------- launch ---------------------------------------------------
extern "C" void kernel_launch(void* const* d_in, const int* in_sizes, int n_in,
                              void* d_out, int out_size, void* d_ws, size_t ws_size,
                              hipStream_t stream) {
  const float* x     = (const float*)d_in[0];
  const float* gamma = (const float*)d_in[1];
  const float* beta  = (const float*)d_in[2];
  const float* w_qkv = (const float*)d_in[3];
  const float* w_out = (const float*)d_in[4];
  float* out = (float*)d_out;

  float* A     = (float*)d_ws;                        // 64
  float* Bc    = A + 64;                              // 64
  float* qkv   = Bc + 64;                             // 442368 floats
  float* out_v = qkv + (size_t)B_SZ * 3 * C_IN * HW_; // 147456 floats

  bn_stats_kernel<<<64, 256, 0, stream>>>(x, gamma, beta, A, Bc);
  conv3x3_v2<3, true, false><<<512, 160, 0, stream>>>(x, w_qkv, A, Bc, nullptr, qkv, 192);
  attn_v2<<<256, 576, 0, stream>>>(qkv, out_v);
  conv3x3_v2<1, false, true><<<512, 160, 0, stream>>>(out_v, w_out, nullptr, nullptr, x, out, 64);
}

// Round 3
// 61.819 us; speedup vs baseline: 2.7884x; 2.2218x over previous
//
#include <hip/hip_runtime.h>
#include <math.h>

#define B_SZ 4
#define C_IN 64
#define HW_ 576

typedef _Float16 h2 __attribute__((ext_vector_type(2)));
typedef _Float16 h4 __attribute__((ext_vector_type(4)));

static __device__ __forceinline__ h2 lo2(h4 v) { return __builtin_shufflevector(v, v, 0, 1); }
static __device__ __forceinline__ h2 hi2(h4 v) { return __builtin_shufflevector(v, v, 2, 3); }

static __device__ __forceinline__ float dot2(h2 a, h2 b, float c) {
#if __has_builtin(__builtin_amdgcn_fdot2)
  return __builtin_amdgcn_fdot2(a, b, c, false);
#else
  return c + (float)a.x * (float)b.x + (float)a.y * (float)b.y;
#endif
}

// Packed input geometry: per (b, icp) plane of 26 rows x 28 cols of h2
// (ic pair), halo = zeros, entry (r,e) = pixel (y=r-1, x=e-1).
#define PPLANE 728           // 26*28
#define XH_N   (B_SZ * 32 * PPLANE)   // 93184 h2 entries
#define WQH_N  (192 * 32 * 9)         // 55296
#define WOH_N  (64 * 32 * 9)          // 18432
#define QKVP_STRIDE (B_SZ * 192 * HW_)  // 442368 floats per partial
#define OUTP_STRIDE (B_SZ * 64 * HW_)   // 147456

// ---------------- Kernel 1: BN batch-stats -> per-channel affine -----------
__global__ __launch_bounds__(256)
void bn_stats_kernel(const float* __restrict__ x, const float* __restrict__ gamma,
                     const float* __restrict__ beta, float* __restrict__ A,
                     float* __restrict__ Bc) {
  const int c = blockIdx.x;
  const int tid = threadIdx.x;
  __shared__ float red[8];
  float s = 0.f, ss = 0.f;
  for (int j = tid; j < B_SZ * HW_; j += 256) {
    int b = j / HW_, i = j - b * HW_;
    float v = x[(b * C_IN + c) * HW_ + i];
    s += v; ss = fmaf(v, v, ss);
  }
#pragma unroll
  for (int off = 32; off > 0; off >>= 1) {
    s += __shfl_down(s, off);
    ss += __shfl_down(ss, off);
  }
  if ((tid & 63) == 0) { red[tid >> 6] = s; red[4 + (tid >> 6)] = ss; }
  __syncthreads();
  if (tid == 0) {
    s  = red[0] + red[1] + red[2] + red[3];
    ss = red[4] + red[5] + red[6] + red[7];
    const float inv_n = 1.f / (B_SZ * HW_);
    float mean = s * inv_n;
    float var  = ss * inv_n - mean * mean;
    float a = rsqrtf(var + 1e-5f) * gamma[c];
    A[c]  = a;
    Bc[c] = fmaf(-mean, a, beta[c]);
  }
}

// ---------------- Kernel 2: pack xn (BN applied) + weights into f16 --------
// grid = 652 * 256 = 166912 = XH_N + WQH_N + WOH_N exactly.
__global__ __launch_bounds__(256)
void pack_kernel(const float* __restrict__ x, const float* __restrict__ A,
                 const float* __restrict__ Bc, const float* __restrict__ wq,
                 const float* __restrict__ wo, h2* __restrict__ xh,
                 h2* __restrict__ wqh, h2* __restrict__ woh) {
  int idx = blockIdx.x * 256 + threadIdx.x;
  if (idx < XH_N) {
    int b = idx / (32 * PPLANE);
    int r0 = idx - b * (32 * PPLANE);
    int icp = r0 / PPLANE;
    int rr = r0 - icp * PPLANE;
    int rrow = rr / 28, e = rr - rrow * 28;
    int yy = rrow - 1, xx = e - 1;
    float f0 = 0.f, f1 = 0.f;
    if ((unsigned)yy < 24u && (unsigned)xx < 24u) {
      int c0 = icp * 2;
      int base = ((b * C_IN + c0) * HW_) + yy * 24 + xx;
      f0 = fmaf(x[base], A[c0], Bc[c0]);
      f1 = fmaf(x[base + HW_], A[c0 + 1], Bc[c0 + 1]);
    }
    h2 v; v.x = (_Float16)f0; v.y = (_Float16)f1;
    xh[idx] = v;
  } else if (idx < XH_N + WQH_N) {
    int t0 = idx - XH_N;            // layout ((g*32+icp)*4 + o)*9 + t, g<48
    int t = t0 % 9; int r = t0 / 9;
    int o = r % 4; r /= 4;
    int icp = r % 32; int g = r / 32;
    int oc = g * 4 + o, ic = icp * 2;
    h2 v;
    v.x = (_Float16)wq[(oc * C_IN + ic) * 9 + t];
    v.y = (_Float16)wq[(oc * C_IN + ic + 1) * 9 + t];
    wqh[t0] = v;
  } else {
    int t0 = idx - XH_N - WQH_N;    // layout ((g*32+icp)*2 + o)*9 + t, g<32
    int t = t0 % 9; int r = t0 / 9;
    int o = r % 2; r /= 2;
    int icp = r % 32; int g = r / 32;
    int oc = g * 2 + o, ic = icp * 2;
    h2 v;  // scale by 4096 to avoid f16 subnormals (w_out ~ 7e-5)
    v.x = (_Float16)(wo[(oc * C_IN + ic) * 9 + t] * 4096.f);
    v.y = (_Float16)(wo[(oc * C_IN + ic + 1) * 9 + t] * 4096.f);
    woh[t0] = v;
  }
}

// ---------------- Kernel 3/5: conv via f16 dot2, split-K partials ----------
// grid = B * groups * iccN blocks, 288 threads. Thread = 2 output px
// (y = tid/12, x0 = 2*(tid%12)). No LDS: reads pre-padded global planes.
template <int OCG>
__global__ __launch_bounds__(288)
void conv_h(const h2* __restrict__ xin, const h2* __restrict__ wpk,
            float* __restrict__ part, int groups, int iccN, int icpPer, int OC) {
  int bid = blockIdx.x;
  const int icc = bid % iccN; bid /= iccN;
  const int g = bid % groups;
  const int b = bid / groups;
  const int tid = threadIdx.x;
  const int y = tid / 12, x0 = (tid % 12) * 2;

  float acc[OCG][2];
#pragma unroll
  for (int o = 0; o < OCG; ++o) { acc[o][0] = 0.f; acc[o][1] = 0.f; }

  const int icp0 = icc * icpPer;
  for (int i = 0; i < icpPer; ++i) {
    const int icp = icp0 + i;
    const h2* wp = wpk + (size_t)(g * 32 + icp) * (OCG * 9);
    h2 W[OCG * 9];
#pragma unroll
    for (int t = 0; t < OCG * 9; ++t) W[t] = wp[t];
    const h2* dp = xin + ((size_t)(b * 32 + icp) * PPLANE + y * 28 + x0);
    h4 r0a = *(const h4*)(dp);      h4 r0b = *(const h4*)(dp + 2);
    h4 r1a = *(const h4*)(dp + 28); h4 r1b = *(const h4*)(dp + 30);
    h4 r2a = *(const h4*)(dp + 56); h4 r2b = *(const h4*)(dp + 58);
#pragma unroll
    for (int o = 0; o < OCG; ++o) {
      const int wb = o * 9;
      float a0 = acc[o][0], a1 = acc[o][1];
      a0 = dot2(lo2(r0a), W[wb + 0], a0);  a1 = dot2(hi2(r0a), W[wb + 0], a1);
      a0 = dot2(hi2(r0a), W[wb + 1], a0);  a1 = dot2(lo2(r0b), W[wb + 1], a1);
      a0 = dot2(lo2(r0b), W[wb + 2], a0);  a1 = dot2(hi2(r0b), W[wb + 2], a1);
      a0 = dot2(lo2(r1a), W[wb + 3], a0);  a1 = dot2(hi2(r1a), W[wb + 3], a1);
      a0 = dot2(hi2(r1a), W[wb + 4], a0);  a1 = dot2(lo2(r1b), W[wb + 4], a1);
      a0 = dot2(lo2(r1b), W[wb + 5], a0);  a1 = dot2(hi2(r1b), W[wb + 5], a1);
      a0 = dot2(lo2(r2a), W[wb + 6], a0);  a1 = dot2(hi2(r2a), W[wb + 6], a1);
      a0 = dot2(hi2(r2a), W[wb + 7], a0);  a1 = dot2(lo2(r2b), W[wb + 7], a1);
      a0 = dot2(lo2(r2b), W[wb + 8], a0);  a1 = dot2(hi2(r2b), W[wb + 8], a1);
      acc[o][0] = a0; acc[o][1] = a1;
    }
  }
#pragma unroll
  for (int o = 0; o < OCG; ++o) {
    size_t idx = (((size_t)icc * B_SZ + b) * OC + (g * OCG + o)) * HW_ + y * 24 + x0;
    *reinterpret_cast<float2*>(part + idx) = make_float2(acc[o][0], acc[o][1]);
  }
}

// ---------------- Kernel 4: rank-1 attention, writes packed f16 out_v ------
__global__ __launch_bounds__(576)
void attn_h(const float* __restrict__ qkvp, int nparts, h2* __restrict__ outv) {
  const int bc = blockIdx.x;
  const int b = bc >> 6, c = bc & 63;
  const int tid = threadIdx.x;
  __shared__ __align__(16) float2 kvs[HW_];
  __shared__ float red[20];

  size_t qi = (size_t)(b * 192 + c) * HW_ + tid;
  float q = 0.f, kk = 0.f, vv = 0.f;
  for (int p = 0; p < nparts; ++p) {
    const float* base = qkvp + (size_t)p * QKVP_STRIDE;
    q  += base[qi];
    kk += base[qi + 64 * HW_];
    vv += base[qi + 128 * HW_];
  }
  kvs[tid] = make_float2(kk, vv);
  float kmax = kk, kmin = kk;
#pragma unroll
  for (int off = 32; off > 0; off >>= 1) {
    kmax = fmaxf(kmax, __shfl_down(kmax, off));
    kmin = fminf(kmin, __shfl_down(kmin, off));
  }
  const int wid = tid >> 6;
  if ((tid & 63) == 0) { red[wid] = kmax; red[10 + wid] = kmin; }
  __syncthreads();
  kmax = red[0]; kmin = red[10];
#pragma unroll
  for (int w = 1; w < 9; ++w) {
    kmax = fmaxf(kmax, red[w]); kmin = fminf(kmin, red[10 + w]);
  }

  const float scale_l2e = 0.125f * 1.44269504088896341f;
  const float s = q * scale_l2e;
  const float m = (s >= 0.f) ? s * kmax : s * kmin;
  float n0 = 0.f, n1 = 0.f, n2 = 0.f, n3 = 0.f;
  float d0 = 0.f, d1 = 0.f, d2 = 0.f, d3 = 0.f;
  for (int i = 0; i < HW_; i += 4) {
    float4 p0 = *reinterpret_cast<const float4*>(&kvs[i]);      // k0,v0,k1,v1
    float4 p1 = *reinterpret_cast<const float4*>(&kvs[i + 2]);  // k2,v2,k3,v3
    float e0 = exp2f(fmaf(s, p0.x, -m));
    float e1 = exp2f(fmaf(s, p0.z, -m));
    float e2 = exp2f(fmaf(s, p1.x, -m));
    float e3 = exp2f(fmaf(s, p1.z, -m));
    d0 += e0; n0 = fmaf(e0, p0.y, n0);
    d1 += e1; n1 = fmaf(e1, p0.w, n1);
    d2 += e2; n2 = fmaf(e2, p1.y, n2);
    d3 += e3; n3 = fmaf(e3, p1.w, n3);
  }
  float r = (n0 + n1 + n2 + n3) / (d0 + d1 + d2 + d3);

  const int icp = c >> 1, hc = c & 1;
  _Float16* plane = reinterpret_cast<_Float16*>(outv + ((size_t)(b * 32) + icp) * PPLANE);
  const int y = tid / 24, xx = tid - y * 24;
  plane[((y + 1) * 28 + (xx + 1)) * 2 + hc] = (_Float16)r;
  if (tid < 100) {   // zero halo (rows 0,25 cols0..25; cols 0,25 rows 1..24)
    int rrow, e;
    if (tid < 26)      { rrow = 0;           e = tid; }
    else if (tid < 52) { rrow = 25;          e = tid - 26; }
    else if (tid < 76) { rrow = tid - 52 + 1; e = 0; }
    else               { rrow = tid - 76 + 1; e = 25; }
    plane[(rrow * 28 + e) * 2 + hc] = (_Float16)0.f;
  }
}

// ---------------- Kernel 6: out = x + (1/4096) * sum(parts) ----------------
__global__ __launch_bounds__(256)
void final_add(const float* __restrict__ x, const float* __restrict__ parts,
               int nparts, float* __restrict__ out) {
  const int i = (blockIdx.x * 256 + threadIdx.x) * 4;
  float4 r = *reinterpret_cast<const float4*>(x + i);
  const float inv = 1.f / 4096.f;
  for (int p = 0; p < nparts; ++p) {
    float4 t = *reinterpret_cast<const float4*>(parts + (size_t)p * OUTP_STRIDE + i);
    r.x = fmaf(t.x, inv, r.x); r.y = fmaf(t.y, inv, r.y);
    r.z = fmaf(t.z, inv, r.z); r.w = fmaf(t.w, inv, r.w);
  }
  *reinterpret_cast<float4*>(out + i) = r;
}

// ---------------- launch ---------------------------------------------------
extern "C" void kernel_launch(void* const* d_in, const int* in_sizes, int n_in,
                              void* d_out, int out_size, void* d_ws, size_t ws_size,
                              hipStream_t stream) {
  const float* x     = (const float*)d_in[0];
  const float* gamma = (const float*)d_in[1];
  const float* beta  = (const float*)d_in[2];
  const float* w_qkv = (const float*)d_in[3];
  const float* w_out = (const float*)d_in[4];
  float* out = (float*)d_out;

  float* A   = (float*)d_ws;
  float* Bc  = A + 64;
  h2*  xh    = (h2*)(Bc + 64);
  h2*  wqh   = xh + XH_N;
  h2*  woh   = wqh + WQH_N;
  h2*  outv  = woh + WOH_N;
  float* parts = (float*)(outv + XH_N);   // qkv partials; reused for out partials

  const size_t base_f = 64 + 64 + XH_N + WQH_N + WOH_N + XH_N;
  int icc = 1;
  if (ws_size >= (base_f + 4 * (size_t)QKVP_STRIDE) * 4) icc = 4;
  else if (ws_size >= (base_f + 2 * (size_t)QKVP_STRIDE) * 4) icc = 2;

  bn_stats_kernel<<<64, 256, 0, stream>>>(x, gamma, beta, A, Bc);
  pack_kernel<<<652, 256, 0, stream>>>(x, A, Bc, w_qkv, w_out, xh, wqh, woh);
  conv_h<4><<<B_SZ * 48 * icc, 288, 0, stream>>>(xh, wqh, parts, 48, icc, 32 / icc, 192);
  attn_h<<<256, 576, 0, stream>>>(parts, icc, outv);
  conv_h<2><<<B_SZ * 32 * icc, 288, 0, stream>>>(outv, woh, parts, 32, icc, 32 / icc, 64);
  final_add<<<144, 256, 0, stream>>>(x, parts, icc, out);
}

// Round 4
// 50.061 us; speedup vs baseline: 3.4433x; 1.2349x over previous
//
#include <hip/hip_runtime.h>
#include <math.h>

#define B_SZ 4
#define C_IN 64
#define HW_ 576

typedef _Float16 h2 __attribute__((ext_vector_type(2)));
typedef _Float16 h4 __attribute__((ext_vector_type(4)));

static __device__ __forceinline__ h2 lo2(h4 v) { return __builtin_shufflevector(v, v, 0, 1); }
static __device__ __forceinline__ h2 hi2(h4 v) { return __builtin_shufflevector(v, v, 2, 3); }

static __device__ __forceinline__ float dot2(h2 a, h2 b, float c) {
#if __has_builtin(__builtin_amdgcn_fdot2)
  return __builtin_amdgcn_fdot2(a, b, c, false);
#else
  return c + (float)a.x * (float)b.x + (float)a.y * (float)b.y;
#endif
}

// Packed input geometry: per (b, icp) plane of 26 rows x 28 cols of h2
// (ic pair), halo = zeros, entry (r,e) = pixel (y=r-1, x=e-1).
#define PPLANE 728                    // 26*28
#define XH_N   (B_SZ * 32 * PPLANE)   // 93184 h2 entries
#define WQH_N  (192 * 32 * 9)         // 55296
#define WOH_N  (64 * 32 * 9)          // 18432
#define QKVP_STRIDE (B_SZ * 192 * HW_)  // 442368 floats per partial
#define OUTP_STRIDE (B_SZ * 64 * HW_)   // 147456

// ---------------- Kernel 1: BN batch-stats -> per-channel affine -----------
__global__ __launch_bounds__(256)
void bn_stats_kernel(const float* __restrict__ x, const float* __restrict__ gamma,
                     const float* __restrict__ beta, float* __restrict__ A,
                     float* __restrict__ Bc) {
  const int c = blockIdx.x;
  const int tid = threadIdx.x;
  __shared__ float red[8];
  float s = 0.f, ss = 0.f;
  for (int j = tid; j < B_SZ * HW_; j += 256) {
    int b = j / HW_, i = j - b * HW_;
    float v = x[(b * C_IN + c) * HW_ + i];
    s += v; ss = fmaf(v, v, ss);
  }
#pragma unroll
  for (int off = 32; off > 0; off >>= 1) {
    s += __shfl_down(s, off);
    ss += __shfl_down(ss, off);
  }
  if ((tid & 63) == 0) { red[tid >> 6] = s; red[4 + (tid >> 6)] = ss; }
  __syncthreads();
  if (tid == 0) {
    s  = red[0] + red[1] + red[2] + red[3];
    ss = red[4] + red[5] + red[6] + red[7];
    const float inv_n = 1.f / (B_SZ * HW_);
    float mean = s * inv_n;
    float var  = ss * inv_n - mean * mean;
    float a = rsqrtf(var + 1e-5f) * gamma[c];
    A[c]  = a;
    Bc[c] = fmaf(-mean, a, beta[c]);
  }
}

// ---------------- Kernel 2: pack xn (BN applied) + weights into f16 --------
// grid = 652 * 256 = 166912 = XH_N + WQH_N + WOH_N exactly.
__global__ __launch_bounds__(256)
void pack_kernel(const float* __restrict__ x, const float* __restrict__ A,
                 const float* __restrict__ Bc, const float* __restrict__ wq,
                 const float* __restrict__ wo, h2* __restrict__ xh,
                 h2* __restrict__ wqh, h2* __restrict__ woh) {
  int idx = blockIdx.x * 256 + threadIdx.x;
  if (idx < XH_N) {
    int b = idx / (32 * PPLANE);
    int r0 = idx - b * (32 * PPLANE);
    int icp = r0 / PPLANE;
    int rr = r0 - icp * PPLANE;
    int rrow = rr / 28, e = rr - rrow * 28;
    int yy = rrow - 1, xx = e - 1;
    float f0 = 0.f, f1 = 0.f;
    if ((unsigned)yy < 24u && (unsigned)xx < 24u) {
      int c0 = icp * 2;
      int base = ((b * C_IN + c0) * HW_) + yy * 24 + xx;
      f0 = fmaf(x[base], A[c0], Bc[c0]);
      f1 = fmaf(x[base + HW_], A[c0 + 1], Bc[c0 + 1]);
    }
    h2 v; v.x = (_Float16)f0; v.y = (_Float16)f1;
    xh[idx] = v;
  } else if (idx < XH_N + WQH_N) {
    int t0 = idx - XH_N;            // layout ((g*32+icp)*4 + o)*9 + t, g<48
    int t = t0 % 9; int r = t0 / 9;
    int o = r % 4; r /= 4;
    int icp = r % 32; int g = r / 32;
    int oc = g * 4 + o, ic = icp * 2;
    h2 v;
    v.x = (_Float16)wq[(oc * C_IN + ic) * 9 + t];
    v.y = (_Float16)wq[(oc * C_IN + ic + 1) * 9 + t];
    wqh[t0] = v;
  } else {
    int t0 = idx - XH_N - WQH_N;    // layout ((g*32+icp)*2 + o)*9 + t, g<32
    int t = t0 % 9; int r = t0 / 9;
    int o = r % 2; r /= 2;
    int icp = r % 32; int g = r / 32;
    int oc = g * 2 + o, ic = icp * 2;
    h2 v;  // scale by 4096 to avoid f16 subnormals (w_out ~ 7e-5)
    v.x = (_Float16)(wo[(oc * C_IN + ic) * 9 + t] * 4096.f);
    v.y = (_Float16)(wo[(oc * C_IN + ic + 1) * 9 + t] * 4096.f);
    woh[t0] = v;
  }
}

// ---------------- Kernel 3/5: conv via f16 dot2, split-K, LDS weights ------
// Block = 288*nSub threads; sub = tid/288 covers split-K slice
// iccIdx = (bid%nPairs)*nSub + sub. Thread r=tid%288 owns 2 px: y=r/12,
// x0=2*(r%12). Weights staged once in LDS; data read from pre-padded global.
template <int OCG>
__global__ __launch_bounds__(576)
void conv_h(const h2* __restrict__ xin, const h2* __restrict__ wpk,
            float* __restrict__ part, int groups, int nPairs, int nSub,
            int icpPer, int OC) {
  int bid = blockIdx.x;
  const int pair = bid % nPairs; bid /= nPairs;
  const int g = bid % groups;
  const int b = bid / groups;
  const int tid = threadIdx.x;
  const int sub = tid / 288;
  const int r = tid - sub * 288;
  const int y = r / 12, x0 = (r % 12) * 2;
  const int iccIdx = pair * nSub + sub;
  const int icp0 = iccIdx * icpPer;

  __shared__ h2 Wl[OCG * 9 * 32];
  {
    const int tot = nSub * icpPer * OCG * 9;
    const h2* src = wpk + (size_t)(g * 32 + pair * nSub * icpPer) * (OCG * 9);
    for (int t = tid; t < tot; t += blockDim.x) Wl[t] = src[t];
  }
  __syncthreads();
  const h2* myW = Wl + sub * icpPer * OCG * 9;

  float acc[OCG][2];
#pragma unroll
  for (int o = 0; o < OCG; ++o) { acc[o][0] = 0.f; acc[o][1] = 0.f; }

  for (int i = 0; i < icpPer; ++i) {
    const int icp = icp0 + i;
    const h2* wp = myW + i * (OCG * 9);
    h2 W[OCG * 9];
#pragma unroll
    for (int t = 0; t < OCG * 9; ++t) W[t] = wp[t];
    const h2* dp = xin + ((size_t)(b * 32 + icp) * PPLANE + y * 28 + x0);
    h4 r0a = *(const h4*)(dp);      h4 r0b = *(const h4*)(dp + 2);
    h4 r1a = *(const h4*)(dp + 28); h4 r1b = *(const h4*)(dp + 30);
    h4 r2a = *(const h4*)(dp + 56); h4 r2b = *(const h4*)(dp + 58);
#pragma unroll
    for (int o = 0; o < OCG; ++o) {
      const int wb = o * 9;
      float a0 = acc[o][0], a1 = acc[o][1];
      a0 = dot2(lo2(r0a), W[wb + 0], a0);  a1 = dot2(hi2(r0a), W[wb + 0], a1);
      a0 = dot2(hi2(r0a), W[wb + 1], a0);  a1 = dot2(lo2(r0b), W[wb + 1], a1);
      a0 = dot2(lo2(r0b), W[wb + 2], a0);  a1 = dot2(hi2(r0b), W[wb + 2], a1);
      a0 = dot2(lo2(r1a), W[wb + 3], a0);  a1 = dot2(hi2(r1a), W[wb + 3], a1);
      a0 = dot2(hi2(r1a), W[wb + 4], a0);  a1 = dot2(lo2(r1b), W[wb + 4], a1);
      a0 = dot2(lo2(r1b), W[wb + 5], a0);  a1 = dot2(hi2(r1b), W[wb + 5], a1);
      a0 = dot2(lo2(r2a), W[wb + 6], a0);  a1 = dot2(hi2(r2a), W[wb + 6], a1);
      a0 = dot2(hi2(r2a), W[wb + 7], a0);  a1 = dot2(lo2(r2b), W[wb + 7], a1);
      a0 = dot2(lo2(r2b), W[wb + 8], a0);  a1 = dot2(hi2(r2b), W[wb + 8], a1);
      acc[o][0] = a0; acc[o][1] = a1;
    }
  }
#pragma unroll
  for (int o = 0; o < OCG; ++o) {
    size_t idx = (((size_t)iccIdx * B_SZ + b) * OC + (g * OCG + o)) * HW_ + y * 24 + x0;
    *reinterpret_cast<float2*>(part + idx) = make_float2(acc[o][0], acc[o][1]);
  }
}

// ---------------- Kernel 4: rank-1 attention, writes packed f16 out_v ------
__global__ __launch_bounds__(576)
void attn_h(const float* __restrict__ qkvp, int nparts, h2* __restrict__ outv) {
  const int bc = blockIdx.x;
  const int b = bc >> 6, c = bc & 63;
  const int tid = threadIdx.x;
  __shared__ __align__(16) float2 kvs[HW_];
  __shared__ float red[20];

  size_t qi = (size_t)(b * 192 + c) * HW_ + tid;
  float q = 0.f, kk = 0.f, vv = 0.f;
  for (int p = 0; p < nparts; ++p) {
    const float* base = qkvp + (size_t)p * QKVP_STRIDE;
    q  += base[qi];
    kk += base[qi + 64 * HW_];
    vv += base[qi + 128 * HW_];
  }
  kvs[tid] = make_float2(kk, vv);
  float kmax = kk, kmin = kk;
#pragma unroll
  for (int off = 32; off > 0; off >>= 1) {
    kmax = fmaxf(kmax, __shfl_down(kmax, off));
    kmin = fminf(kmin, __shfl_down(kmin, off));
  }
  const int wid = tid >> 6;
  if ((tid & 63) == 0) { red[wid] = kmax; red[10 + wid] = kmin; }
  __syncthreads();
  kmax = red[0]; kmin = red[10];
#pragma unroll
  for (int w = 1; w < 9; ++w) {
    kmax = fmaxf(kmax, red[w]); kmin = fminf(kmin, red[10 + w]);
  }

  const float scale_l2e = 0.125f * 1.44269504088896341f;
  const float s = q * scale_l2e;
  const float m = (s >= 0.f) ? s * kmax : s * kmin;
  float n0 = 0.f, n1 = 0.f, n2 = 0.f, n3 = 0.f;
  float d0 = 0.f, d1 = 0.f, d2 = 0.f, d3 = 0.f;
  for (int i = 0; i < HW_; i += 4) {
    float4 p0 = *reinterpret_cast<const float4*>(&kvs[i]);      // k0,v0,k1,v1
    float4 p1 = *reinterpret_cast<const float4*>(&kvs[i + 2]);  // k2,v2,k3,v3
    float e0 = __builtin_amdgcn_exp2f(fmaf(s, p0.x, -m));
    float e1 = __builtin_amdgcn_exp2f(fmaf(s, p0.z, -m));
    float e2 = __builtin_amdgcn_exp2f(fmaf(s, p1.x, -m));
    float e3 = __builtin_amdgcn_exp2f(fmaf(s, p1.z, -m));
    d0 += e0; n0 = fmaf(e0, p0.y, n0);
    d1 += e1; n1 = fmaf(e1, p0.w, n1);
    d2 += e2; n2 = fmaf(e2, p1.y, n2);
    d3 += e3; n3 = fmaf(e3, p1.w, n3);
  }
  float rr = (n0 + n1 + n2 + n3) / (d0 + d1 + d2 + d3);

  const int icp = c >> 1, hc = c & 1;
  _Float16* plane = reinterpret_cast<_Float16*>(outv + ((size_t)(b * 32) + icp) * PPLANE);
  const int y = tid / 24, xx = tid - y * 24;
  plane[((y + 1) * 28 + (xx + 1)) * 2 + hc] = (_Float16)rr;
  if (tid < 100) {   // zero halo (rows 0,25 cols0..25; cols 0,25 rows 1..24)
    int rrow, e;
    if (tid < 26)      { rrow = 0;            e = tid; }
    else if (tid < 52) { rrow = 25;           e = tid - 26; }
    else if (tid < 76) { rrow = tid - 52 + 1; e = 0; }
    else               { rrow = tid - 76 + 1; e = 25; }
    plane[(rrow * 28 + e) * 2 + hc] = (_Float16)0.f;
  }
}

// ---------------- Kernel 6: out = x + (1/4096) * sum(parts) ----------------
__global__ __launch_bounds__(256)
void final_add(const float* __restrict__ x, const float* __restrict__ parts,
               int nparts, float* __restrict__ out) {
  const int i = (blockIdx.x * 256 + threadIdx.x) * 4;
  float4 r = *reinterpret_cast<const float4*>(x + i);
  const float inv = 1.f / 4096.f;
  for (int p = 0; p < nparts; ++p) {
    float4 t = *reinterpret_cast<const float4*>(parts + (size_t)p * OUTP_STRIDE + i);
    r.x = fmaf(t.x, inv, r.x); r.y = fmaf(t.y, inv, r.y);
    r.z = fmaf(t.z, inv, r.z); r.w = fmaf(t.w, inv, r.w);
  }
  *reinterpret_cast<float4*>(out + i) = r;
}

// ---------------- launch ---------------------------------------------------
extern "C" void kernel_launch(void* const* d_in, const int* in_sizes, int n_in,
                              void* d_out, int out_size, void* d_ws, size_t ws_size,
                              hipStream_t stream) {
  const float* x     = (const float*)d_in[0];
  const float* gamma = (const float*)d_in[1];
  const float* beta  = (const float*)d_in[2];
  const float* w_qkv = (const float*)d_in[3];
  const float* w_out = (const float*)d_in[4];
  float* out = (float*)d_out;

  float* A   = (float*)d_ws;
  float* Bc  = A + 64;
  h2*  xh    = (h2*)(Bc + 64);
  h2*  wqh   = xh + XH_N;
  h2*  woh   = wqh + WQH_N;
  h2*  outv  = woh + WOH_N;
  float* parts = (float*)(outv + XH_N);   // qkv partials; reused for out partials

  const size_t base_f = 64 + 64 + XH_N + WQH_N + WOH_N + XH_N;
  int icc = 1;
  if (ws_size >= (base_f + 4 * (size_t)QKVP_STRIDE) * 4) icc = 4;
  else if (ws_size >= (base_f + 2 * (size_t)QKVP_STRIDE) * 4) icc = 2;
  const int nSub = (icc >= 2) ? 2 : 1;
  const int nPairs = icc / nSub;
  const int icpPer = 32 / icc;

  bn_stats_kernel<<<64, 256, 0, stream>>>(x, gamma, beta, A, Bc);
  pack_kernel<<<652, 256, 0, stream>>>(x, A, Bc, w_qkv, w_out, xh, wqh, woh);
  conv_h<4><<<B_SZ * 48 * nPairs, 288 * nSub, 0, stream>>>(
      xh, wqh, parts, 48, nPairs, nSub, icpPer, 192);
  attn_h<<<256, 576, 0, stream>>>(parts, icc, outv);
  conv_h<2><<<B_SZ * 32 * nPairs, 288 * nSub, 0, stream>>>(
      outv, woh, parts, 32, nPairs, nSub, icpPer, 64);
  final_add<<<144, 256, 0, stream>>>(x, parts, icc, out);
}